// Round 5
// baseline (194.846 us; speedup 1.0000x reference)
//
#include <hip/hip_runtime.h>

#define NEGV -10000000000.0f
constexpr int Bn = 64, Tn = 512, Ln = 64;
constexpr int CK = 32;          // chunk length
constexpr int QP = 68;          // padded LDS row pitch (bf16 elems)
constexpr float L2E = 1.4426950408889634f;
constexpr float LN2 = 0.6931471805599453f;

typedef float f32x16 __attribute__((ext_vector_type(16)));
typedef __bf16 bf16x8 __attribute__((ext_vector_type(8)));
typedef unsigned int u32;
typedef unsigned short u16;

__device__ inline float waveMaxF(float v) {
#pragma unroll
    for (int off = 32; off > 0; off >>= 1)
        v = fmaxf(v, __shfl_xor(v, off, 64));
    return v;
}
__device__ inline u32 packbf(float a, float b) {
    u32 ua = __float_as_uint(a) + 0x8000u;
    u32 ub = __float_as_uint(b) + 0x8000u;
    return (ua >> 16) | (ub & 0xffff0000u);
}
__device__ inline float lo16f(u32 d) { return __uint_as_float(d << 16); }
__device__ inline float hi16f(u32 d) { return __uint_as_float(d & 0xffff0000u); }
__device__ inline float fexp2(float x) { return __builtin_amdgcn_exp2f(x); }
__device__ inline float flog2(float x) { return __builtin_amdgcn_logf(x); }

// ---------------- serial matvec chunk scan (round-2 verified) -------------
template <bool FIRST>
__device__ void chunk_scan(const float* __restrict__ emb,
                           float* __restrict__ outb, float* uLDS,
                           const float* Ecol, float entry, int t0, int j, int len,
                           float trSj, float* aLastOut, float* aFinalOut) {
    const bool edge = (j == 0) || (j == Ln - 1);
    float emq[4];
#pragma unroll
    for (int tt = 0; tt < 4; ++tt) {
        float v = emb[(t0 + tt) * Ln + j];
        emq[tt] = edge ? NEGV : v;
    }
    float aPrev, mPrev, u;
    int tauStart;
    if (FIRST) {
        float a0 = trSj + emq[0];
        outb[t0 * Ln + j] = a0;
        aPrev = a0;
        mPrev = __shfl(a0, 1, 64);
        u = __expf(a0 - mPrev);
        tauStart = 1;
    } else {
        aPrev = entry;
        mPrev = __shfl(entry, 1, 64);
        u = __expf(entry - mPrev);
        tauStart = 0;
    }
    float aLast = *aLastOut;
#pragma unroll 4
    for (int tau = tauStart; tau < CK; ++tau) {
        const int t = t0 + tau;
        uLDS[j] = u;
        const float em_t = emq[tau & 3];
        const int tp = tau + 4;
        if (tp < CK) {
            float v = emb[(t0 + tp) * Ln + j];
            emq[tp & 3] = edge ? NEGV : v;
        }
        float mNext = __shfl(aPrev, 1, 64);
        float cf = __expf(em_t + (mPrev - mNext));
        float acc0 = 0.f, acc1 = 0.f, acc2 = 0.f, acc3 = 0.f;
        const float4* u4 = reinterpret_cast<const float4*>(uLDS);
#pragma unroll
        for (int i4 = 0; i4 < 16; ++i4) {
            float4 uv = u4[i4];
            acc0 = fmaf(uv.x, Ecol[4 * i4 + 0], acc0);
            acc1 = fmaf(uv.y, Ecol[4 * i4 + 1], acc1);
            acc2 = fmaf(uv.z, Ecol[4 * i4 + 2], acc2);
            acc3 = fmaf(uv.w, Ecol[4 * i4 + 3], acc3);
        }
        float S = (acc0 + acc1) + (acc2 + acc3);
        float lg = __logf(S);
        lg = (S > 0.f) ? lg : NEGV;
        float a_t = em_t + (mPrev + lg);
        outb[t * Ln + j] = a_t;
        if (t == len - 1) aLast = a_t;
        u = S * cf;
        aPrev = a_t;
        mPrev = mNext;
    }
    *aLastOut = aLast;
    *aFinalOut = aPrev;
}

// ============ PASS A: chunk-0 scan + transfer matrices (register-resident Q) ============
__global__ __launch_bounds__(128) void crf_passA(const float* __restrict__ em,
                                                 const float* __restrict__ tr,
                                                 float* __restrict__ out,
                                                 float* __restrict__ wsE,
                                                 float* __restrict__ wsS) {
    const int b = blockIdx.x & 63;
    const int cix = blockIdx.x >> 6;         // 0..15
    const int J = threadIdx.x >> 6;          // wave id = column group
    const int L = threadIdx.x & 63;          // lane
    __shared__ alignas(16) float gtab[CK * 64];       // 8 KiB
    __shared__ alignas(16) u16 Qlds[64 * QP];         // 8.5 KiB (epilogue only)
    __shared__ alignas(16) float uLDS[64];
    __shared__ float sLDS[2];
    __shared__ float sigLDS[2];

    if (cix == 0) {
        if (J == 1) return;                  // no barriers on this path
        float Ecol[Ln];
#pragma unroll
        for (int i = 0; i < Ln; ++i) Ecol[i] = __expf(tr[i * Ln + L]);
        const float trSj = tr[L];
        const float* emb = em + (size_t)b * Tn * Ln;
        float* outb = out + (size_t)b * Tn * Ln;
        float dummyLast = 0.f, aFinal;
        chunk_scan<true>(emb, outb, uLDS, Ecol, 0.f, 0, L, /*len*/ -1, trSj, &dummyLast, &aFinal);
        wsE[b * 1024 + 1 * 64 + L] = aFinal;
        return;
    }

    const int t0 = CK * cix;
    const int c31 = L & 31;
    const int h = L >> 5;

    // ---- gtab fill (split by wave), vectorized butterfly row-max
    {
        float orig[16], sv[16];
        const int tb = t0 + 16 * J;
#pragma unroll
        for (int r = 0; r < 16; ++r) {
            float v = em[((size_t)b * Tn + (tb + r)) * Ln + L];
            if (L == 0 || L == Ln - 1) v = NEGV;
            orig[r] = v;
            sv[r] = v;
        }
#pragma unroll
        for (int off = 32; off > 0; off >>= 1) {
#pragma unroll
            for (int r = 0; r < 16; ++r)
                sv[r] = fmaxf(sv[r], __shfl_xor(sv[r], off, 64));
        }
        float ssum = 0.f;
#pragma unroll
        for (int r = 0; r < 16; ++r) {
            gtab[(16 * J + r) * 64 + L] = __expf(orig[r] - sv[r]);
            ssum += sv[r];
        }
        if (L == 0) sLDS[J] = ssum;
    }
    __syncthreads();
    const float sSum = sLDS[0] + sLDS[1];

    // ---- A-frags: A[m][k] = exp(tr[k][m]), m = 32I + c31, k = 16kc + 8h + q
    uint4 Ap[2][4];
#pragma unroll
    for (int I = 0; I < 2; ++I)
#pragma unroll
        for (int kc = 0; kc < 4; ++kc) {
            float e[8];
#pragma unroll
            for (int q = 0; q < 8; ++q) {
                int k = 16 * kc + 8 * h + q;
                e[q] = __expf(tr[k * Ln + 32 * I + c31]);
            }
            Ap[I][kc] = make_uint4(packbf(e[0], e[1]), packbf(e[2], e[3]),
                                   packbf(e[4], e[5]), packbf(e[6], e[7]));
        }

    // ---- Q0 in registers: P[I][rg] holds k = 32I+8rg+4h+e of column n
    const int n = 32 * J + c31;
    uint2 P[2][4];
#pragma unroll
    for (int I = 0; I < 2; ++I)
#pragma unroll
        for (int rg = 0; rg < 4; ++rg) {
            const int k0 = 32 * I + 8 * rg + 4 * h;
            float4 tv = *(const float4*)&tr[n * Ln + k0];
            float4 gv = *(const float4*)&gtab[k0];
            float v0 = __expf(tv.x) * gv.x, v1 = __expf(tv.y) * gv.y;
            float v2 = __expf(tv.z) * gv.z, v3 = __expf(tv.w) * gv.w;
            P[I][rg] = make_uint2(packbf(v0, v1), packbf(v2, v3));
        }

    // ---- main loop: barrier-free, LDS-free; C->B relayout via shfl_xor(32)
    float sig_w = 0.f;
    float wm = 1.0f;
    const f32x16 Z = (f32x16)(0.0f);
    for (int tau = 1; tau < CK; ++tau) {
        uint4 Bp[4];
#pragma unroll
        for (int kc = 0; kc < 4; ++kc) {
            const int I = kc >> 1;
            uint2 keep = P[I][2 * (kc & 1) + h];
            uint2 send = P[I][2 * (kc & 1) + (1 - h)];
            uint2 recv;
            recv.x = (u32)__shfl_xor((int)send.x, 32, 64);
            recv.y = (u32)__shfl_xor((int)send.y, 32, 64);
            Bp[kc] = (h == 0) ? make_uint4(keep.x, keep.y, recv.x, recv.y)
                              : make_uint4(recv.x, recv.y, keep.x, keep.y);
        }
        f32x16 acc0 = Z, acc1 = Z;
#pragma unroll
        for (int kc = 0; kc < 4; ++kc) {
            acc0 = __builtin_amdgcn_mfma_f32_32x32x16_bf16(
                __builtin_bit_cast(bf16x8, Ap[0][kc]),
                __builtin_bit_cast(bf16x8, Bp[kc]), acc0, 0, 0, 0);
            acc1 = __builtin_amdgcn_mfma_f32_32x32x16_bf16(
                __builtin_bit_cast(bf16x8, Ap[1][kc]),
                __builtin_bit_cast(bf16x8, Bp[kc]), acc1, 0, 0, 0);
        }
        const bool doRescale = ((tau & 3) == 0);
        const bool doMeasure = ((tau & 3) == 2);
        float rr = 1.0f;
        if (doRescale) {
            rr = 1.0f / wm;
            sig_w += __logf(wm);
        }
        float lmax = 0.f;
#pragma unroll
        for (int I = 0; I < 2; ++I)
#pragma unroll
            for (int rg = 0; rg < 4; ++rg) {
                const int k0 = 32 * I + 8 * rg + 4 * h;
                float4 G = *(const float4*)&gtab[tau * 64 + k0];
                float v0 = (I ? acc1 : acc0)[4 * rg + 0] * (G.x * rr);
                float v1 = (I ? acc1 : acc0)[4 * rg + 1] * (G.y * rr);
                float v2 = (I ? acc1 : acc0)[4 * rg + 2] * (G.z * rr);
                float v3 = (I ? acc1 : acc0)[4 * rg + 3] * (G.w * rr);
                if (doMeasure) lmax = fmaxf(lmax, fmaxf(fmaxf(v0, v1), fmaxf(v2, v3)));
                P[I][rg] = make_uint2(packbf(v0, v1), packbf(v2, v3));
            }
        if (doMeasure) wm = waveMaxF(lmax);
    }

    // ---- spill P to Qlds once, then per-row normalize + store (round-4 epilogue)
#pragma unroll
    for (int I = 0; I < 2; ++I)
#pragma unroll
        for (int rg = 0; rg < 4; ++rg) {
            const int k0 = 32 * I + 8 * rg + 4 * h;
            *(uint2*)&Qlds[n * QP + k0] = P[I][rg];
        }
    if (L == 0) sigLDS[J] = sSum + sig_w;
    __syncthreads();
    const float sg0 = sigLDS[0], sg1 = sigLDS[1];
    const float smax = fmaxf(sg0, sg1);
    const float fh = __expf((h ? sg1 : sg0) - smax);
    const int r = 32 * J + c31;
    float rv[32];
    float lmaxr = 0.f;
#pragma unroll
    for (int i = 0; i < 32; ++i) {
        float v = __uint_as_float(((u32)Qlds[(32 * h + i) * QP + r]) << 16) * fh;
        rv[i] = v;
        lmaxr = fmaxf(lmaxr, v);
    }
    float rmax = fmaxf(lmaxr, __shfl_xor(lmaxr, 32, 64));
    float inv = (rmax > 0.f) ? 1.0f / rmax : 0.f;
    float sj = (rmax > 0.f) ? smax + __logf(rmax) : 0.f;
    u32* og = (u32*)out + (size_t)b * (Tn * Ln) + (size_t)cix * (CK * Ln) + r * 32 + h * 16;
#pragma unroll
    for (int w8 = 0; w8 < 4; ++w8) {
        uint4 w;
        w.x = packbf(rv[8 * w8 + 0] * inv, rv[8 * w8 + 1] * inv);
        w.y = packbf(rv[8 * w8 + 2] * inv, rv[8 * w8 + 3] * inv);
        w.z = packbf(rv[8 * w8 + 4] * inv, rv[8 * w8 + 5] * inv);
        w.w = packbf(rv[8 * w8 + 6] * inv, rv[8 * w8 + 7] * inv);
        *(uint4*)(og + 4 * w8) = w;
    }
    if (h == 0) wsS[b * 1024 + cix * 64 + r] = sj;
}

// ================= PASS B: serial boundary combine (unchanged) =================
__global__ __launch_bounds__(64) void crf_passB(const float* __restrict__ out,
                                                float* __restrict__ wsE,
                                                const float* __restrict__ wsS) {
    const int b = blockIdx.x;
    const int j = threadIdx.x;
    __shared__ alignas(16) float uL[64];
    const u32* Qbase = (const u32*)out + (size_t)b * (Tn * Ln);

    float e = wsE[b * 1024 + 1 * 64 + j];
    uint4 nxt[8];
    float signxt = wsS[b * 1024 + 1 * 64 + j];
#pragma unroll
    for (int r = 0; r < 8; ++r) nxt[r] = *(const uint4*)(Qbase + 1 * (CK * Ln) + j * 32 + 4 * r);

#pragma unroll
    for (int c = 1; c <= 14; ++c) {
        uint4 cur[8];
#pragma unroll
        for (int r = 0; r < 8; ++r) cur[r] = nxt[r];
        float sig = signxt;
        if (c < 14) {
#pragma unroll
            for (int r = 0; r < 8; ++r)
                nxt[r] = *(const uint4*)(Qbase + (size_t)(c + 1) * (CK * Ln) + j * 32 + 4 * r);
            signxt = wsS[b * 1024 + (c + 1) * 64 + j];
        }
        float m = __shfl(e, 1, 64);
        uL[j] = __expf(e - m);
        const float4* u4 = reinterpret_cast<const float4*>(uL);
        float S = 0.f;
#pragma unroll
        for (int i4 = 0; i4 < 16; ++i4) {
            float4 uv = u4[i4];
            u32 d0 = ((const u32*)cur)[2 * i4];
            u32 d1 = ((const u32*)cur)[2 * i4 + 1];
            S = fmaf(uv.x, lo16f(d0), S);
            S = fmaf(uv.y, hi16f(d0), S);
            S = fmaf(uv.z, lo16f(d1), S);
            S = fmaf(uv.w, hi16f(d1), S);
        }
        float a;
        if (S > 0.f) a = m + sig + __logf(S);
        else a = m + NEGV + ((j == 0) ? NEGV : 0.f);
        e = a;
        wsE[b * 1024 + (c + 1) * 64 + j] = e;
    }
}

// ========== PASS C: batch-matrix MFMA alpha recompute (1 block per chunk) ==========
__global__ __launch_bounds__(128) void crf_passC(const float* __restrict__ em,
                                                 const float* __restrict__ tr,
                                                 float* __restrict__ out,
                                                 const float* __restrict__ wsE) {
    const int cix = 1 + blockIdx.x;          // 1..15
    const int J = threadIdx.x >> 6;
    const int L = threadIdx.x & 63;
    const int h = L >> 5, c31 = L & 31;
    const int b = 32 * J + c31;              // batch = this lane's column
    const int t0 = CK * cix;

    // A-frags: E^T, identical to passA
    uint4 Ap[2][4];
#pragma unroll
    for (int I = 0; I < 2; ++I)
#pragma unroll
        for (int kc = 0; kc < 4; ++kc) {
            float e[8];
#pragma unroll
            for (int q = 0; q < 8; ++q) {
                int k = 16 * kc + 8 * h + q;
                e[q] = __expf(tr[k * Ln + 32 * I + c31]);
            }
            Ap[I][kc] = make_uint4(packbf(e[0], e[1]), packbf(e[2], e[3]),
                                   packbf(e[4], e[5]), packbf(e[6], e[7]));
        }

    // entry: V0[k][b] = exp(alpha_entry[k] - sigma_b)
    const float* we = wsE + b * 1024 + cix * 64;
    float sig;
    uint2 P[2][4];
    {
        float4 av[2][4];
        float mx = -3e38f;
#pragma unroll
        for (int I = 0; I < 2; ++I)
#pragma unroll
            for (int rg = 0; rg < 4; ++rg) {
                const int k0 = 32 * I + 8 * rg + 4 * h;
                float4 a4 = *(const float4*)&we[k0];
                av[I][rg] = a4;
                mx = fmaxf(mx, fmaxf(fmaxf(a4.x, a4.y), fmaxf(a4.z, a4.w)));
            }
        mx = fmaxf(mx, __shfl_xor(mx, 32, 64));
        sig = mx;
#pragma unroll
        for (int I = 0; I < 2; ++I)
#pragma unroll
            for (int rg = 0; rg < 4; ++rg) {
                float4 a4 = av[I][rg];
                float v0 = fexp2((a4.x - sig) * L2E), v1 = fexp2((a4.y - sig) * L2E);
                float v2 = fexp2((a4.z - sig) * L2E), v3 = fexp2((a4.w - sig) * L2E);
                P[I][rg] = make_uint2(packbf(v0, v1), packbf(v2, v3));
            }
    }

    const float* pe = em + ((size_t)b * Tn + t0) * Ln;
    float* po = out + ((size_t)b * Tn + t0) * Ln;

    float4 e0[2][4];
#pragma unroll
    for (int I = 0; I < 2; ++I)
#pragma unroll
        for (int rg = 0; rg < 4; ++rg)
            e0[I][rg] = *(const float4*)&pe[32 * I + 8 * rg + 4 * h];

    float wmUse = 1.0f;
    const f32x16 Z = (f32x16)(0.0f);
    for (int tau = 0; tau < CK; ++tau) {
        const bool even = ((tau & 1) == 0);
        float rr = 1.0f, dsig = 0.0f;
        if (even && tau >= 2) {
            rr = 1.0f / wmUse;
            dsig = LN2 * flog2(wmUse);
        }
        uint4 Bp[4];
#pragma unroll
        for (int kc = 0; kc < 4; ++kc) {
            const int I = kc >> 1;
            uint2 keep = P[I][2 * (kc & 1) + h];
            uint2 send = P[I][2 * (kc & 1) + (1 - h)];
            uint2 recv;
            recv.x = (u32)__shfl_xor((int)send.x, 32, 64);
            recv.y = (u32)__shfl_xor((int)send.y, 32, 64);
            Bp[kc] = (h == 0) ? make_uint4(keep.x, keep.y, recv.x, recv.y)
                              : make_uint4(recv.x, recv.y, keep.x, keep.y);
        }
        f32x16 acc0 = Z, acc1 = Z;
#pragma unroll
        for (int kc = 0; kc < 4; ++kc) {
            acc0 = __builtin_amdgcn_mfma_f32_32x32x16_bf16(
                __builtin_bit_cast(bf16x8, Ap[0][kc]),
                __builtin_bit_cast(bf16x8, Bp[kc]), acc0, 0, 0, 0);
            acc1 = __builtin_amdgcn_mfma_f32_32x32x16_bf16(
                __builtin_bit_cast(bf16x8, Ap[1][kc]),
                __builtin_bit_cast(bf16x8, Bp[kc]), acc1, 0, 0, 0);
        }
        float4 e1[2][4];
        if (tau + 1 < CK) {
#pragma unroll
            for (int I = 0; I < 2; ++I)
#pragma unroll
                for (int rg = 0; rg < 4; ++rg)
                    e1[I][rg] = *(const float4*)&pe[(tau + 1) * Ln + 32 * I + 8 * rg + 4 * h];
        }
        float lmax = 0.f;
#pragma unroll
        for (int I = 0; I < 2; ++I)
#pragma unroll
            for (int rg = 0; rg < 4; ++rg) {
                const int k0 = 32 * I + 8 * rg + 4 * h;
                float4 ev = e0[I][rg];
                if (k0 == 0) ev.x = NEGV;            // n==0  (START col)
                if (k0 == 60) ev.w = NEGV;           // n==63 (END col)
                float c0 = (I ? acc1 : acc0)[4 * rg + 0];
                float c1 = (I ? acc1 : acc0)[4 * rg + 1];
                float c2 = (I ? acc1 : acc0)[4 * rg + 2];
                float c3 = (I ? acc1 : acc0)[4 * rg + 3];
                // alpha = em' + log(acc) + sigma  (acc==0 -> NEG clamp)
                float4 al;
                al.x = ev.x + ((c0 > 0.f) ? LN2 * flog2(c0) + sig : NEGV);
                al.y = ev.y + ((c1 > 0.f) ? LN2 * flog2(c1) + sig : NEGV);
                al.z = ev.z + ((c2 > 0.f) ? LN2 * flog2(c2) + sig : NEGV);
                al.w = ev.w + ((c3 > 0.f) ? LN2 * flog2(c3) + sig : NEGV);
                *(float4*)&po[tau * Ln + k0] = al;
                // V_new = acc * g * rr,  g = exp(em')
                float v0 = c0 * (fexp2(ev.x * L2E) * rr);
                float v1 = c1 * (fexp2(ev.y * L2E) * rr);
                float v2 = c2 * (fexp2(ev.z * L2E) * rr);
                float v3 = c3 * (fexp2(ev.w * L2E) * rr);
                if (even) lmax = fmaxf(lmax, fmaxf(fmaxf(v0, v1), fmaxf(v2, v3)));
                P[I][rg] = make_uint2(packbf(v0, v1), packbf(v2, v3));
            }
        if (even) wmUse = fmaxf(lmax, __shfl_xor(lmax, 32, 64));
        sig += dsig;                                 // applies to V_new (next step's input)
        if (tau + 1 < CK) {
#pragma unroll
            for (int I = 0; I < 2; ++I)
#pragma unroll
                for (int rg = 0; rg < 4; ++rg) e0[I][rg] = e1[I][rg];
        }
    }
}

// ================= PASS D: logZ from finished alphas =================
__global__ __launch_bounds__(64) void crf_logZ(const float* __restrict__ tr,
                                               const int* __restrict__ lens,
                                               float* __restrict__ out) {
    const int b = blockIdx.x;
    const int j = threadIdx.x;
    float a = out[(size_t)b * Tn * Ln + (size_t)(lens[b] - 1) * Ln + j] + tr[j * Ln + (Ln - 1)];
    float m2 = waveMaxF(a);
    float e2 = __expf(a - m2);
#pragma unroll
    for (int off = 32; off > 0; off >>= 1)
        e2 += __shfl_xor(e2, off, 64);
    if (j == 0) out[(size_t)Bn * Tn * Ln + b] = m2 + __logf(e2);
}

// ================= fallback: round-2 single kernel =================
__global__ __launch_bounds__(64) void crf_fallback(const float* __restrict__ em,
                                                   const float* __restrict__ tr,
                                                   const int* __restrict__ lens,
                                                   float* __restrict__ out) {
    const int b = blockIdx.x;
    const int j = threadIdx.x;
    __shared__ alignas(16) float uLDS[Ln];
    float E[Ln];
#pragma unroll
    for (int i = 0; i < Ln; ++i) E[i] = __expf(tr[i * Ln + j]);
    const float trSj = tr[j];
    const float trEj = tr[j * Ln + (Ln - 1)];
    const int len = lens[b];
    const bool edge = (j == 0) || (j == Ln - 1);
    const float* emb = em + (size_t)b * Tn * Ln;
    float* outb = out + (size_t)b * Tn * Ln;
    float emq[4];
#pragma unroll
    for (int tt = 0; tt < 4; ++tt) {
        float v = emb[tt * Ln + j];
        emq[tt] = edge ? NEGV : v;
    }
    float a = trSj + emq[0];
    outb[j] = a;
    float aPrev = a, aLast = a;
    float mPrev = __shfl(a, 1, 64);
    float u = __expf(a - mPrev);
#pragma unroll 4
    for (int t = 1; t < Tn; ++t) {
        uLDS[j] = u;
        const float em_t = emq[t & 3];
        const int tp = t + 4;
        if (tp < Tn) {
            float v = emb[tp * Ln + j];
            emq[tp & 3] = edge ? NEGV : v;
        }
        float mNext = __shfl(aPrev, 1, 64);
        float cf = __expf(em_t + (mPrev - mNext));
        float acc0 = 0.f, acc1 = 0.f, acc2 = 0.f, acc3 = 0.f;
        const float4* u4 = reinterpret_cast<const float4*>(uLDS);
#pragma unroll
        for (int i4 = 0; i4 < 16; ++i4) {
            float4 uv = u4[i4];
            acc0 = fmaf(uv.x, E[4 * i4 + 0], acc0);
            acc1 = fmaf(uv.y, E[4 * i4 + 1], acc1);
            acc2 = fmaf(uv.z, E[4 * i4 + 2], acc2);
            acc3 = fmaf(uv.w, E[4 * i4 + 3], acc3);
        }
        float S = (acc0 + acc1) + (acc2 + acc3);
        float lg = __logf(S);
        lg = (S > 0.f) ? lg : NEGV;
        float a_t = em_t + (mPrev + lg);
        outb[t * Ln + j] = a_t;
        if (t == len - 1) aLast = a_t;
        u = S * cf;
        aPrev = a_t;
        mPrev = mNext;
    }
    float last = aLast + trEj;
    float m2 = last;
#pragma unroll
    for (int off = 32; off > 0; off >>= 1)
        m2 = fmaxf(m2, __shfl_xor(m2, off, 64));
    float e2 = __expf(last - m2);
#pragma unroll
    for (int off = 32; off > 0; off >>= 1)
        e2 += __shfl_xor(e2, off, 64);
    if (j == 0) out[(size_t)Bn * Tn * Ln + b] = m2 + __logf(e2);
}

extern "C" void kernel_launch(void* const* d_in, const int* in_sizes, int n_in,
                              void* d_out, int out_size, void* d_ws, size_t ws_size,
                              hipStream_t stream) {
    const float* em = (const float*)d_in[0];
    const float* tr = (const float*)d_in[1];
    const int* lens = (const int*)d_in[2];
    float* out = (float*)d_out;
    const size_t wsNeed = 2u * 64 * 16 * 64 * sizeof(float);   // 512 KiB
    if (ws_size >= wsNeed) {
        float* wsE = (float*)d_ws;
        float* wsS = wsE + 64 * 16 * 64;
        crf_passA<<<dim3(1024), dim3(128), 0, stream>>>(em, tr, out, wsE, wsS);
        crf_passB<<<dim3(64), dim3(64), 0, stream>>>(out, wsE, wsS);
        crf_passC<<<dim3(15), dim3(128), 0, stream>>>(em, tr, out, wsE);
        crf_logZ<<<dim3(64), dim3(64), 0, stream>>>(tr, lens, out);
    } else {
        crf_fallback<<<dim3(Bn), dim3(64), 0, stream>>>(em, tr, lens, out);
    }
}

// Round 6
// 173.185 us; speedup vs baseline: 1.1251x; 1.1251x over previous
//
#include <hip/hip_runtime.h>

#define NEGV -10000000000.0f
constexpr int Bn = 64, Tn = 512, Ln = 64;
constexpr int CK = 32;          // chunk length
constexpr int QP = 68;          // padded LDS row pitch (bf16 elems)
constexpr float L2E = 1.4426950408889634f;
constexpr float LN2 = 0.6931471805599453f;

typedef float f32x16 __attribute__((ext_vector_type(16)));
typedef __bf16 bf16x8 __attribute__((ext_vector_type(8)));
typedef unsigned int u32;
typedef unsigned short u16;

__device__ inline float waveMaxF(float v) {
#pragma unroll
    for (int off = 32; off > 0; off >>= 1)
        v = fmaxf(v, __shfl_xor(v, off, 64));
    return v;
}
__device__ inline u32 packbf(float a, float b) {
    u32 ua = __float_as_uint(a) + 0x8000u;
    u32 ub = __float_as_uint(b) + 0x8000u;
    return (ua >> 16) | (ub & 0xffff0000u);
}
__device__ inline float lo16f(u32 d) { return __uint_as_float(d << 16); }
__device__ inline float hi16f(u32 d) { return __uint_as_float(d & 0xffff0000u); }
__device__ inline float fexp2(float x) { return __builtin_amdgcn_exp2f(x); }
__device__ inline float flog2(float x) { return __builtin_amdgcn_logf(x); }

// ---------------- serial matvec chunk scan (round-2 verified) -------------
template <bool FIRST>
__device__ void chunk_scan(const float* __restrict__ emb,
                           float* __restrict__ outb, float* uLDS,
                           const float* Ecol, float entry, int t0, int j, int len,
                           float trSj, float* aLastOut, float* aFinalOut) {
    const bool edge = (j == 0) || (j == Ln - 1);
    float emq[4];
#pragma unroll
    for (int tt = 0; tt < 4; ++tt) {
        float v = emb[(t0 + tt) * Ln + j];
        emq[tt] = edge ? NEGV : v;
    }
    float aPrev, mPrev, u;
    int tauStart;
    if (FIRST) {
        float a0 = trSj + emq[0];
        outb[t0 * Ln + j] = a0;
        aPrev = a0;
        mPrev = __shfl(a0, 1, 64);
        u = __expf(a0 - mPrev);
        tauStart = 1;
    } else {
        aPrev = entry;
        mPrev = __shfl(entry, 1, 64);
        u = __expf(entry - mPrev);
        tauStart = 0;
    }
    float aLast = *aLastOut;
#pragma unroll 4
    for (int tau = tauStart; tau < CK; ++tau) {
        const int t = t0 + tau;
        uLDS[j] = u;
        const float em_t = emq[tau & 3];
        const int tp = tau + 4;
        if (tp < CK) {
            float v = emb[(t0 + tp) * Ln + j];
            emq[tp & 3] = edge ? NEGV : v;
        }
        float mNext = __shfl(aPrev, 1, 64);
        float cf = __expf(em_t + (mPrev - mNext));
        float acc0 = 0.f, acc1 = 0.f, acc2 = 0.f, acc3 = 0.f;
        const float4* u4 = reinterpret_cast<const float4*>(uLDS);
#pragma unroll
        for (int i4 = 0; i4 < 16; ++i4) {
            float4 uv = u4[i4];
            acc0 = fmaf(uv.x, Ecol[4 * i4 + 0], acc0);
            acc1 = fmaf(uv.y, Ecol[4 * i4 + 1], acc1);
            acc2 = fmaf(uv.z, Ecol[4 * i4 + 2], acc2);
            acc3 = fmaf(uv.w, Ecol[4 * i4 + 3], acc3);
        }
        float S = (acc0 + acc1) + (acc2 + acc3);
        float lg = __logf(S);
        lg = (S > 0.f) ? lg : NEGV;
        float a_t = em_t + (mPrev + lg);
        outb[t * Ln + j] = a_t;
        if (t == len - 1) aLast = a_t;
        u = S * cf;
        aPrev = a_t;
        mPrev = mNext;
    }
    *aLastOut = aLast;
    *aFinalOut = aPrev;
}

// ============ PASS A: chunk-0 scan + transfer matrices (register-resident Q) ============
__global__ __launch_bounds__(128) void crf_passA(const float* __restrict__ em,
                                                 const float* __restrict__ tr,
                                                 float* __restrict__ out,
                                                 float* __restrict__ wsE,
                                                 float* __restrict__ wsS) {
    const int b = blockIdx.x & 63;
    const int cix = blockIdx.x >> 6;         // 0..15
    const int J = threadIdx.x >> 6;          // wave id = column group
    const int L = threadIdx.x & 63;          // lane
    __shared__ alignas(16) float gtab[CK * 64];       // 8 KiB
    __shared__ alignas(16) u16 Qlds[64 * QP];         // 8.5 KiB (epilogue only)
    __shared__ alignas(16) float uLDS[64];
    __shared__ float sLDS[2];
    __shared__ float sigLDS[2];

    if (cix == 0) {
        if (J == 1) return;                  // no barriers on this path
        float Ecol[Ln];
#pragma unroll
        for (int i = 0; i < Ln; ++i) Ecol[i] = __expf(tr[i * Ln + L]);
        const float trSj = tr[L];
        const float* emb = em + (size_t)b * Tn * Ln;
        float* outb = out + (size_t)b * Tn * Ln;
        float dummyLast = 0.f, aFinal;
        chunk_scan<true>(emb, outb, uLDS, Ecol, 0.f, 0, L, /*len*/ -1, trSj, &dummyLast, &aFinal);
        wsE[b * 1024 + 1 * 64 + L] = aFinal;
        return;
    }

    const int t0 = CK * cix;
    const int c31 = L & 31;
    const int h = L >> 5;
    const bool hi = (h != 0);

    // ---- gtab fill (split by wave), vectorized butterfly row-max
    {
        float orig[16], sv[16];
        const int tb = t0 + 16 * J;
#pragma unroll
        for (int r = 0; r < 16; ++r) {
            float v = em[((size_t)b * Tn + (tb + r)) * Ln + L];
            if (L == 0 || L == Ln - 1) v = NEGV;
            orig[r] = v;
            sv[r] = v;
        }
#pragma unroll
        for (int off = 32; off > 0; off >>= 1) {
#pragma unroll
            for (int r = 0; r < 16; ++r)
                sv[r] = fmaxf(sv[r], __shfl_xor(sv[r], off, 64));
        }
        float ssum = 0.f;
#pragma unroll
        for (int r = 0; r < 16; ++r) {
            gtab[(16 * J + r) * 64 + L] = __expf(orig[r] - sv[r]);
            ssum += sv[r];
        }
        if (L == 0) sLDS[J] = ssum;
    }
    __syncthreads();
    const float sSum = sLDS[0] + sLDS[1];

    // ---- A-frags: A[m][k] = exp(tr[k][m]), m = 32I + c31, k = 16kc + 8h + q
    uint4 Ap[2][4];
#pragma unroll
    for (int I = 0; I < 2; ++I)
#pragma unroll
        for (int kc = 0; kc < 4; ++kc) {
            float e[8];
#pragma unroll
            for (int q = 0; q < 8; ++q) {
                int k = 16 * kc + 8 * h + q;
                e[q] = __expf(tr[k * Ln + 32 * I + c31]);
            }
            Ap[I][kc] = make_uint4(packbf(e[0], e[1]), packbf(e[2], e[3]),
                                   packbf(e[4], e[5]), packbf(e[6], e[7]));
        }

    // ---- Q0 in registers: P[I][rg] holds k = 32I+8rg+4h+e of column n
    const int n = 32 * J + c31;
    uint2 P[2][4];
#pragma unroll
    for (int I = 0; I < 2; ++I)
#pragma unroll
        for (int rg = 0; rg < 4; ++rg) {
            const int k0 = 32 * I + 8 * rg + 4 * h;
            float4 tv = *(const float4*)&tr[n * Ln + k0];
            float4 gv = *(const float4*)&gtab[k0];
            float v0 = __expf(tv.x) * gv.x, v1 = __expf(tv.y) * gv.y;
            float v2 = __expf(tv.z) * gv.z, v3 = __expf(tv.w) * gv.w;
            P[I][rg] = make_uint2(packbf(v0, v1), packbf(v2, v3));
        }

    // ---- main loop: barrier-free, LDS-free; C->B relayout via shfl_xor(32)
    // NOTE: value-selects (cndmask) only — runtime-indexing P would demote it to scratch.
    float sig_w = 0.f;
    float wm = 1.0f;
    const f32x16 Z = (f32x16)(0.0f);
    for (int tau = 1; tau < CK; ++tau) {
        uint4 Bp[4];
#pragma unroll
        for (int kc = 0; kc < 4; ++kc) {
            const int I = kc >> 1;
            const int rgB = 2 * (kc & 1);
            uint2 pe = P[I][rgB];            // rg even: holds k=...+4*h (this lane's h)
            uint2 po = P[I][rgB + 1];        // rg odd
            uint2 keep, send;
            keep.x = hi ? po.x : pe.x;  keep.y = hi ? po.y : pe.y;
            send.x = hi ? pe.x : po.x;  send.y = hi ? pe.y : po.y;
            uint2 recv;
            recv.x = (u32)__shfl_xor((int)send.x, 32, 64);
            recv.y = (u32)__shfl_xor((int)send.y, 32, 64);
            Bp[kc].x = hi ? recv.x : keep.x;
            Bp[kc].y = hi ? recv.y : keep.y;
            Bp[kc].z = hi ? keep.x : recv.x;
            Bp[kc].w = hi ? keep.y : recv.y;
        }
        f32x16 acc0 = Z, acc1 = Z;
#pragma unroll
        for (int kc = 0; kc < 4; ++kc) {
            acc0 = __builtin_amdgcn_mfma_f32_32x32x16_bf16(
                __builtin_bit_cast(bf16x8, Ap[0][kc]),
                __builtin_bit_cast(bf16x8, Bp[kc]), acc0, 0, 0, 0);
            acc1 = __builtin_amdgcn_mfma_f32_32x32x16_bf16(
                __builtin_bit_cast(bf16x8, Ap[1][kc]),
                __builtin_bit_cast(bf16x8, Bp[kc]), acc1, 0, 0, 0);
        }
        const bool doRescale = ((tau & 3) == 0);
        const bool doMeasure = ((tau & 3) == 2);
        float rr = 1.0f;
        if (doRescale) {
            rr = 1.0f / wm;
            sig_w += __logf(wm);
        }
        float lmax = 0.f;
#pragma unroll
        for (int I = 0; I < 2; ++I)
#pragma unroll
            for (int rg = 0; rg < 4; ++rg) {
                const int k0 = 32 * I + 8 * rg + 4 * h;
                float4 G = *(const float4*)&gtab[tau * 64 + k0];
                float v0 = (I ? acc1 : acc0)[4 * rg + 0] * (G.x * rr);
                float v1 = (I ? acc1 : acc0)[4 * rg + 1] * (G.y * rr);
                float v2 = (I ? acc1 : acc0)[4 * rg + 2] * (G.z * rr);
                float v3 = (I ? acc1 : acc0)[4 * rg + 3] * (G.w * rr);
                if (doMeasure) lmax = fmaxf(lmax, fmaxf(fmaxf(v0, v1), fmaxf(v2, v3)));
                P[I][rg] = make_uint2(packbf(v0, v1), packbf(v2, v3));
            }
        if (doMeasure) wm = waveMaxF(lmax);
    }

    // ---- spill P to Qlds once, then per-row normalize + store (round-4 epilogue)
#pragma unroll
    for (int I = 0; I < 2; ++I)
#pragma unroll
        for (int rg = 0; rg < 4; ++rg) {
            const int k0 = 32 * I + 8 * rg + 4 * h;
            *(uint2*)&Qlds[n * QP + k0] = P[I][rg];
        }
    if (L == 0) sigLDS[J] = sSum + sig_w;
    __syncthreads();
    const float sg0 = sigLDS[0], sg1 = sigLDS[1];
    const float smax = fmaxf(sg0, sg1);
    const float fh = __expf((hi ? sg1 : sg0) - smax);
    const int r = 32 * J + c31;
    float rv[32];
    float lmaxr = 0.f;
#pragma unroll
    for (int i = 0; i < 32; ++i) {
        float v = __uint_as_float(((u32)Qlds[(32 * h + i) * QP + r]) << 16) * fh;
        rv[i] = v;
        lmaxr = fmaxf(lmaxr, v);
    }
    float rmax = fmaxf(lmaxr, __shfl_xor(lmaxr, 32, 64));
    float inv = (rmax > 0.f) ? 1.0f / rmax : 0.f;
    float sj = (rmax > 0.f) ? smax + __logf(rmax) : 0.f;
    u32* og = (u32*)out + (size_t)b * (Tn * Ln) + (size_t)cix * (CK * Ln) + r * 32 + h * 16;
#pragma unroll
    for (int w8 = 0; w8 < 4; ++w8) {
        uint4 w;
        w.x = packbf(rv[8 * w8 + 0] * inv, rv[8 * w8 + 1] * inv);
        w.y = packbf(rv[8 * w8 + 2] * inv, rv[8 * w8 + 3] * inv);
        w.z = packbf(rv[8 * w8 + 4] * inv, rv[8 * w8 + 5] * inv);
        w.w = packbf(rv[8 * w8 + 6] * inv, rv[8 * w8 + 7] * inv);
        *(uint4*)(og + 4 * w8) = w;
    }
    if (h == 0) wsS[b * 1024 + cix * 64 + r] = sj;
}

// ================= PASS B: serial boundary combine (unchanged) =================
__global__ __launch_bounds__(64) void crf_passB(const float* __restrict__ out,
                                                float* __restrict__ wsE,
                                                const float* __restrict__ wsS) {
    const int b = blockIdx.x;
    const int j = threadIdx.x;
    __shared__ alignas(16) float uL[64];
    const u32* Qbase = (const u32*)out + (size_t)b * (Tn * Ln);

    float e = wsE[b * 1024 + 1 * 64 + j];
    uint4 nxt[8];
    float signxt = wsS[b * 1024 + 1 * 64 + j];
#pragma unroll
    for (int r = 0; r < 8; ++r) nxt[r] = *(const uint4*)(Qbase + 1 * (CK * Ln) + j * 32 + 4 * r);

#pragma unroll
    for (int c = 1; c <= 14; ++c) {
        uint4 cur[8];
#pragma unroll
        for (int r = 0; r < 8; ++r) cur[r] = nxt[r];
        float sig = signxt;
        if (c < 14) {
#pragma unroll
            for (int r = 0; r < 8; ++r)
                nxt[r] = *(const uint4*)(Qbase + (size_t)(c + 1) * (CK * Ln) + j * 32 + 4 * r);
            signxt = wsS[b * 1024 + (c + 1) * 64 + j];
        }
        float m = __shfl(e, 1, 64);
        uL[j] = __expf(e - m);
        const float4* u4 = reinterpret_cast<const float4*>(uL);
        float S = 0.f;
#pragma unroll
        for (int i4 = 0; i4 < 16; ++i4) {
            float4 uv = u4[i4];
            u32 d0 = ((const u32*)cur)[2 * i4];
            u32 d1 = ((const u32*)cur)[2 * i4 + 1];
            S = fmaf(uv.x, lo16f(d0), S);
            S = fmaf(uv.y, hi16f(d0), S);
            S = fmaf(uv.z, lo16f(d1), S);
            S = fmaf(uv.w, hi16f(d1), S);
        }
        float a;
        if (S > 0.f) a = m + sig + __logf(S);
        else a = m + NEGV + ((j == 0) ? NEGV : 0.f);
        e = a;
        wsE[b * 1024 + (c + 1) * 64 + j] = e;
    }
}

// ========== PASS C: batch-matrix MFMA alpha recompute (1 block per chunk) ==========
__global__ __launch_bounds__(128) void crf_passC(const float* __restrict__ em,
                                                 const float* __restrict__ tr,
                                                 float* __restrict__ out,
                                                 const float* __restrict__ wsE) {
    const int cix = 1 + blockIdx.x;          // 1..15
    const int J = threadIdx.x >> 6;
    const int L = threadIdx.x & 63;
    const int h = L >> 5, c31 = L & 31;
    const bool hi = (h != 0);
    const int b = 32 * J + c31;              // batch = this lane's column
    const int t0 = CK * cix;

    // A-frags: E^T, identical to passA
    uint4 Ap[2][4];
#pragma unroll
    for (int I = 0; I < 2; ++I)
#pragma unroll
        for (int kc = 0; kc < 4; ++kc) {
            float e[8];
#pragma unroll
            for (int q = 0; q < 8; ++q) {
                int k = 16 * kc + 8 * h + q;
                e[q] = __expf(tr[k * Ln + 32 * I + c31]);
            }
            Ap[I][kc] = make_uint4(packbf(e[0], e[1]), packbf(e[2], e[3]),
                                   packbf(e[4], e[5]), packbf(e[6], e[7]));
        }

    // entry: V0[k][b] = exp(alpha_entry[k] - sigma_b)
    const float* we = wsE + b * 1024 + cix * 64;
    float sig;
    uint2 P[2][4];
    {
        float4 av[2][4];
        float mx = -3e38f;
#pragma unroll
        for (int I = 0; I < 2; ++I)
#pragma unroll
            for (int rg = 0; rg < 4; ++rg) {
                const int k0 = 32 * I + 8 * rg + 4 * h;
                float4 a4 = *(const float4*)&we[k0];
                av[I][rg] = a4;
                mx = fmaxf(mx, fmaxf(fmaxf(a4.x, a4.y), fmaxf(a4.z, a4.w)));
            }
        mx = fmaxf(mx, __shfl_xor(mx, 32, 64));
        sig = mx;
#pragma unroll
        for (int I = 0; I < 2; ++I)
#pragma unroll
            for (int rg = 0; rg < 4; ++rg) {
                float4 a4 = av[I][rg];
                float v0 = fexp2((a4.x - sig) * L2E), v1 = fexp2((a4.y - sig) * L2E);
                float v2 = fexp2((a4.z - sig) * L2E), v3 = fexp2((a4.w - sig) * L2E);
                P[I][rg] = make_uint2(packbf(v0, v1), packbf(v2, v3));
            }
    }

    const float* pe = em + ((size_t)b * Tn + t0) * Ln;
    float* po = out + ((size_t)b * Tn + t0) * Ln;

    float4 e0[2][4];
#pragma unroll
    for (int I = 0; I < 2; ++I)
#pragma unroll
        for (int rg = 0; rg < 4; ++rg)
            e0[I][rg] = *(const float4*)&pe[32 * I + 8 * rg + 4 * h];

    float wmUse = 1.0f;
    const f32x16 Z = (f32x16)(0.0f);
    for (int tau = 0; tau < CK; ++tau) {
        const bool even = ((tau & 1) == 0);
        float rr = 1.0f, dsig = 0.0f;
        if (even && tau >= 2) {
            rr = 1.0f / wmUse;
            dsig = LN2 * flog2(wmUse);
        }
        uint4 Bp[4];
#pragma unroll
        for (int kc = 0; kc < 4; ++kc) {
            const int I = kc >> 1;
            const int rgB = 2 * (kc & 1);
            uint2 pe2 = P[I][rgB];
            uint2 po2 = P[I][rgB + 1];
            uint2 keep, send;
            keep.x = hi ? po2.x : pe2.x;  keep.y = hi ? po2.y : pe2.y;
            send.x = hi ? pe2.x : po2.x;  send.y = hi ? pe2.y : po2.y;
            uint2 recv;
            recv.x = (u32)__shfl_xor((int)send.x, 32, 64);
            recv.y = (u32)__shfl_xor((int)send.y, 32, 64);
            Bp[kc].x = hi ? recv.x : keep.x;
            Bp[kc].y = hi ? recv.y : keep.y;
            Bp[kc].z = hi ? keep.x : recv.x;
            Bp[kc].w = hi ? keep.y : recv.y;
        }
        f32x16 acc0 = Z, acc1 = Z;
#pragma unroll
        for (int kc = 0; kc < 4; ++kc) {
            acc0 = __builtin_amdgcn_mfma_f32_32x32x16_bf16(
                __builtin_bit_cast(bf16x8, Ap[0][kc]),
                __builtin_bit_cast(bf16x8, Bp[kc]), acc0, 0, 0, 0);
            acc1 = __builtin_amdgcn_mfma_f32_32x32x16_bf16(
                __builtin_bit_cast(bf16x8, Ap[1][kc]),
                __builtin_bit_cast(bf16x8, Bp[kc]), acc1, 0, 0, 0);
        }
        float4 e1[2][4];
        if (tau + 1 < CK) {
#pragma unroll
            for (int I = 0; I < 2; ++I)
#pragma unroll
                for (int rg = 0; rg < 4; ++rg)
                    e1[I][rg] = *(const float4*)&pe[(tau + 1) * Ln + 32 * I + 8 * rg + 4 * h];
        }
        float lmax = 0.f;
#pragma unroll
        for (int I = 0; I < 2; ++I)
#pragma unroll
            for (int rg = 0; rg < 4; ++rg) {
                const int k0 = 32 * I + 8 * rg + 4 * h;
                float4 ev = e0[I][rg];
                if (k0 == 0) ev.x = NEGV;            // n==0  (START col)
                if (k0 == 60) ev.w = NEGV;           // n==63 (END col)
                float c0 = (I ? acc1 : acc0)[4 * rg + 0];
                float c1 = (I ? acc1 : acc0)[4 * rg + 1];
                float c2 = (I ? acc1 : acc0)[4 * rg + 2];
                float c3 = (I ? acc1 : acc0)[4 * rg + 3];
                float4 al;
                al.x = ev.x + ((c0 > 0.f) ? LN2 * flog2(c0) + sig : NEGV);
                al.y = ev.y + ((c1 > 0.f) ? LN2 * flog2(c1) + sig : NEGV);
                al.z = ev.z + ((c2 > 0.f) ? LN2 * flog2(c2) + sig : NEGV);
                al.w = ev.w + ((c3 > 0.f) ? LN2 * flog2(c3) + sig : NEGV);
                *(float4*)&po[tau * Ln + k0] = al;
                float v0 = c0 * (fexp2(ev.x * L2E) * rr);
                float v1 = c1 * (fexp2(ev.y * L2E) * rr);
                float v2 = c2 * (fexp2(ev.z * L2E) * rr);
                float v3 = c3 * (fexp2(ev.w * L2E) * rr);
                if (even) lmax = fmaxf(lmax, fmaxf(fmaxf(v0, v1), fmaxf(v2, v3)));
                P[I][rg] = make_uint2(packbf(v0, v1), packbf(v2, v3));
            }
        if (even) wmUse = fmaxf(lmax, __shfl_xor(lmax, 32, 64));
        sig += dsig;                                 // applies to V_new (next step's input)
        if (tau + 1 < CK) {
#pragma unroll
            for (int I = 0; I < 2; ++I)
#pragma unroll
                for (int rg = 0; rg < 4; ++rg) e0[I][rg] = e1[I][rg];
        }
    }
}

// ================= PASS D: logZ from finished alphas =================
__global__ __launch_bounds__(64) void crf_logZ(const float* __restrict__ tr,
                                               const int* __restrict__ lens,
                                               float* __restrict__ out) {
    const int b = blockIdx.x;
    const int j = threadIdx.x;
    float a = out[(size_t)b * Tn * Ln + (size_t)(lens[b] - 1) * Ln + j] + tr[j * Ln + (Ln - 1)];
    float m2 = waveMaxF(a);
    float e2 = __expf(a - m2);
#pragma unroll
    for (int off = 32; off > 0; off >>= 1)
        e2 += __shfl_xor(e2, off, 64);
    if (j == 0) out[(size_t)Bn * Tn * Ln + b] = m2 + __logf(e2);
}

// ================= fallback: round-2 single kernel =================
__global__ __launch_bounds__(64) void crf_fallback(const float* __restrict__ em,
                                                   const float* __restrict__ tr,
                                                   const int* __restrict__ lens,
                                                   float* __restrict__ out) {
    const int b = blockIdx.x;
    const int j = threadIdx.x;
    __shared__ alignas(16) float uLDS[Ln];
    float E[Ln];
#pragma unroll
    for (int i = 0; i < Ln; ++i) E[i] = __expf(tr[i * Ln + j]);
    const float trSj = tr[j];
    const float trEj = tr[j * Ln + (Ln - 1)];
    const int len = lens[b];
    const bool edge = (j == 0) || (j == Ln - 1);
    const float* emb = em + (size_t)b * Tn * Ln;
    float* outb = out + (size_t)b * Tn * Ln;
    float emq[4];
#pragma unroll
    for (int tt = 0; tt < 4; ++tt) {
        float v = emb[tt * Ln + j];
        emq[tt] = edge ? NEGV : v;
    }
    float a = trSj + emq[0];
    outb[j] = a;
    float aPrev = a, aLast = a;
    float mPrev = __shfl(a, 1, 64);
    float u = __expf(a - mPrev);
#pragma unroll 4
    for (int t = 1; t < Tn; ++t) {
        uLDS[j] = u;
        const float em_t = emq[t & 3];
        const int tp = t + 4;
        if (tp < Tn) {
            float v = emb[tp * Ln + j];
            emq[tp & 3] = edge ? NEGV : v;
        }
        float mNext = __shfl(aPrev, 1, 64);
        float cf = __expf(em_t + (mPrev - mNext));
        float acc0 = 0.f, acc1 = 0.f, acc2 = 0.f, acc3 = 0.f;
        const float4* u4 = reinterpret_cast<const float4*>(uLDS);
#pragma unroll
        for (int i4 = 0; i4 < 16; ++i4) {
            float4 uv = u4[i4];
            acc0 = fmaf(uv.x, E[4 * i4 + 0], acc0);
            acc1 = fmaf(uv.y, E[4 * i4 + 1], acc1);
            acc2 = fmaf(uv.z, E[4 * i4 + 2], acc2);
            acc3 = fmaf(uv.w, E[4 * i4 + 3], acc3);
        }
        float S = (acc0 + acc1) + (acc2 + acc3);
        float lg = __logf(S);
        lg = (S > 0.f) ? lg : NEGV;
        float a_t = em_t + (mPrev + lg);
        outb[t * Ln + j] = a_t;
        if (t == len - 1) aLast = a_t;
        u = S * cf;
        aPrev = a_t;
        mPrev = mNext;
    }
    float last = aLast + trEj;
    float m2 = last;
#pragma unroll
    for (int off = 32; off > 0; off >>= 1)
        m2 = fmaxf(m2, __shfl_xor(m2, off, 64));
    float e2 = __expf(last - m2);
#pragma unroll
    for (int off = 32; off > 0; off >>= 1)
        e2 += __shfl_xor(e2, off, 64);
    if (j == 0) out[(size_t)Bn * Tn * Ln + b] = m2 + __logf(e2);
}

extern "C" void kernel_launch(void* const* d_in, const int* in_sizes, int n_in,
                              void* d_out, int out_size, void* d_ws, size_t ws_size,
                              hipStream_t stream) {
    const float* em = (const float*)d_in[0];
    const float* tr = (const float*)d_in[1];
    const int* lens = (const int*)d_in[2];
    float* out = (float*)d_out;
    const size_t wsNeed = 2u * 64 * 16 * 64 * sizeof(float);   // 512 KiB
    if (ws_size >= wsNeed) {
        float* wsE = (float*)d_ws;
        float* wsS = wsE + 64 * 16 * 64;
        crf_passA<<<dim3(1024), dim3(128), 0, stream>>>(em, tr, out, wsE, wsS);
        crf_passB<<<dim3(64), dim3(64), 0, stream>>>(out, wsE, wsS);
        crf_passC<<<dim3(15), dim3(128), 0, stream>>>(em, tr, out, wsE);
        crf_logZ<<<dim3(64), dim3(64), 0, stream>>>(tr, lens, out);
    } else {
        crf_fallback<<<dim3(Bn), dim3(64), 0, stream>>>(em, tr, lens, out);
    }
}

// Round 7
// 168.162 us; speedup vs baseline: 1.1587x; 1.0299x over previous
//
#include <hip/hip_runtime.h>

#define NEGV -10000000000.0f
constexpr int Bn = 64, Tn = 512, Ln = 64;
constexpr int CK = 32;          // chunk length
constexpr int QP = 68;          // padded LDS row pitch (bf16 elems)
constexpr float L2E = 1.4426950408889634f;
constexpr float LN2 = 0.6931471805599453f;

typedef float f32x16 __attribute__((ext_vector_type(16)));
typedef __bf16 bf16x8 __attribute__((ext_vector_type(8)));
typedef unsigned int u32;
typedef unsigned short u16;

__device__ inline float waveMaxF(float v) {
#pragma unroll
    for (int off = 32; off > 0; off >>= 1)
        v = fmaxf(v, __shfl_xor(v, off, 64));
    return v;
}
__device__ inline u32 packbf(float a, float b) {
    u32 ua = __float_as_uint(a) + 0x8000u;
    u32 ub = __float_as_uint(b) + 0x8000u;
    return (ua >> 16) | (ub & 0xffff0000u);
}
__device__ inline float lo16f(u32 d) { return __uint_as_float(d << 16); }
__device__ inline float hi16f(u32 d) { return __uint_as_float(d & 0xffff0000u); }
__device__ inline float fexp2(float x) { return __builtin_amdgcn_exp2f(x); }
__device__ inline float flog2(float x) { return __builtin_amdgcn_logf(x); }

// ---------------- serial matvec chunk scan (round-2 verified) -------------
template <bool FIRST>
__device__ void chunk_scan(const float* __restrict__ emb,
                           float* __restrict__ outb, float* uLDS,
                           const float* Ecol, float entry, int t0, int j, int len,
                           float trSj, float* aLastOut, float* aFinalOut) {
    const bool edge = (j == 0) || (j == Ln - 1);
    float emq[4];
#pragma unroll
    for (int tt = 0; tt < 4; ++tt) {
        float v = emb[(t0 + tt) * Ln + j];
        emq[tt] = edge ? NEGV : v;
    }
    float aPrev, mPrev, u;
    int tauStart;
    if (FIRST) {
        float a0 = trSj + emq[0];
        outb[t0 * Ln + j] = a0;
        aPrev = a0;
        mPrev = __shfl(a0, 1, 64);
        u = __expf(a0 - mPrev);
        tauStart = 1;
    } else {
        aPrev = entry;
        mPrev = __shfl(entry, 1, 64);
        u = __expf(entry - mPrev);
        tauStart = 0;
    }
    float aLast = *aLastOut;
#pragma unroll 4
    for (int tau = tauStart; tau < CK; ++tau) {
        const int t = t0 + tau;
        uLDS[j] = u;
        const float em_t = emq[tau & 3];
        const int tp = tau + 4;
        if (tp < CK) {
            float v = emb[(t0 + tp) * Ln + j];
            emq[tp & 3] = edge ? NEGV : v;
        }
        float mNext = __shfl(aPrev, 1, 64);
        float cf = __expf(em_t + (mPrev - mNext));
        float acc0 = 0.f, acc1 = 0.f, acc2 = 0.f, acc3 = 0.f;
        const float4* u4 = reinterpret_cast<const float4*>(uLDS);
#pragma unroll
        for (int i4 = 0; i4 < 16; ++i4) {
            float4 uv = u4[i4];
            acc0 = fmaf(uv.x, Ecol[4 * i4 + 0], acc0);
            acc1 = fmaf(uv.y, Ecol[4 * i4 + 1], acc1);
            acc2 = fmaf(uv.z, Ecol[4 * i4 + 2], acc2);
            acc3 = fmaf(uv.w, Ecol[4 * i4 + 3], acc3);
        }
        float S = (acc0 + acc1) + (acc2 + acc3);
        float lg = __logf(S);
        lg = (S > 0.f) ? lg : NEGV;
        float a_t = em_t + (mPrev + lg);
        outb[t * Ln + j] = a_t;
        if (t == len - 1) aLast = a_t;
        u = S * cf;
        aPrev = a_t;
        mPrev = mNext;
    }
    *aLastOut = aLast;
    *aFinalOut = aPrev;
}

// ============ PASS A: chunk-0 scan + transfer matrices (register-resident Q) ============
__global__ __launch_bounds__(128) void crf_passA(const float* __restrict__ em,
                                                 const float* __restrict__ tr,
                                                 float* __restrict__ out,
                                                 float* __restrict__ wsE,
                                                 float* __restrict__ wsS) {
    const int b = blockIdx.x & 63;
    const int cix = blockIdx.x >> 6;         // 0..15
    const int J = threadIdx.x >> 6;          // wave id = column group
    const int L = threadIdx.x & 63;          // lane
    __shared__ alignas(16) float gtab[CK * 64];       // 8 KiB
    __shared__ alignas(16) u16 Qlds[64 * QP];         // 8.5 KiB (epilogue only)
    __shared__ alignas(16) float uLDS[64];
    __shared__ float sigLDS[2];

    if (cix == 0) {
        if (J == 1) return;                  // no barriers on this path
        float Ecol[Ln];
#pragma unroll
        for (int i = 0; i < Ln; ++i) Ecol[i] = __expf(tr[i * Ln + L]);
        const float trSj = tr[L];
        const float* emb = em + (size_t)b * Tn * Ln;
        float* outb = out + (size_t)b * Tn * Ln;
        float dummyLast = 0.f, aFinal;
        chunk_scan<true>(emb, outb, uLDS, Ecol, 0.f, 0, L, /*len*/ -1, trSj, &dummyLast, &aFinal);
        wsE[b * 1024 + 1 * 64 + L] = aFinal;
        return;
    }

    const int t0 = CK * cix;
    const int c31 = L & 31;
    const int h = L >> 5;
    const bool hi = (h != 0);

    // ---- gtab fill (split by wave): g = exp(em'), NO max-normalize (wm rescale bounds range)
    {
        const int tb = t0 + 16 * J;
#pragma unroll
        for (int rr2 = 0; rr2 < 16; ++rr2) {
            float v = em[((size_t)b * Tn + (tb + rr2)) * Ln + L];
            if (L == 0 || L == Ln - 1) v = NEGV;
            gtab[(16 * J + rr2) * 64 + L] = __expf(v);   // exp(NEGV) == 0 -> masked cols
        }
    }
    __syncthreads();

    // ---- A-frags: A[m][k] = exp(tr[k][m]), m = 32I + c31, k = 16kc + 8h + q
    uint4 Ap[2][4];
#pragma unroll
    for (int I = 0; I < 2; ++I)
#pragma unroll
        for (int kc = 0; kc < 4; ++kc) {
            float e[8];
#pragma unroll
            for (int q = 0; q < 8; ++q) {
                int k = 16 * kc + 8 * h + q;
                e[q] = __expf(tr[k * Ln + 32 * I + c31]);
            }
            Ap[I][kc] = make_uint4(packbf(e[0], e[1]), packbf(e[2], e[3]),
                                   packbf(e[4], e[5]), packbf(e[6], e[7]));
        }

    // ---- Q0 in registers: P[I][rg] holds k = 32I+8rg+4h+e of column n
    const int n = 32 * J + c31;
    uint2 P[2][4];
#pragma unroll
    for (int I = 0; I < 2; ++I)
#pragma unroll
        for (int rg = 0; rg < 4; ++rg) {
            const int k0 = 32 * I + 8 * rg + 4 * h;
            float4 tv = *(const float4*)&tr[n * Ln + k0];
            float4 gv = *(const float4*)&gtab[k0];
            float v0 = __expf(tv.x) * gv.x, v1 = __expf(tv.y) * gv.y;
            float v2 = __expf(tv.z) * gv.z, v3 = __expf(tv.w) * gv.w;
            P[I][rg] = make_uint2(packbf(v0, v1), packbf(v2, v3));
        }

    // ---- main loop: barrier-free, LDS-free; C->B relayout via shfl_xor(32)
    // NOTE: value-selects (cndmask) only — runtime-indexing P would demote it to scratch.
    float sig_w = 0.f;
    float wm = 1.0f;
    const f32x16 Z = (f32x16)(0.0f);
    for (int tau = 1; tau < CK; ++tau) {
        uint4 Bp[4];
#pragma unroll
        for (int kc = 0; kc < 4; ++kc) {
            const int I = kc >> 1;
            const int rgB = 2 * (kc & 1);
            uint2 pe = P[I][rgB];            // rg even: holds k=...+4*h (this lane's h)
            uint2 po = P[I][rgB + 1];        // rg odd
            uint2 keep, send;
            keep.x = hi ? po.x : pe.x;  keep.y = hi ? po.y : pe.y;
            send.x = hi ? pe.x : po.x;  send.y = hi ? pe.y : po.y;
            uint2 recv;
            recv.x = (u32)__shfl_xor((int)send.x, 32, 64);
            recv.y = (u32)__shfl_xor((int)send.y, 32, 64);
            Bp[kc].x = hi ? recv.x : keep.x;
            Bp[kc].y = hi ? recv.y : keep.y;
            Bp[kc].z = hi ? keep.x : recv.x;
            Bp[kc].w = hi ? keep.y : recv.y;
        }
        f32x16 acc0 = Z, acc1 = Z;
#pragma unroll
        for (int kc = 0; kc < 4; ++kc) {
            acc0 = __builtin_amdgcn_mfma_f32_32x32x16_bf16(
                __builtin_bit_cast(bf16x8, Ap[0][kc]),
                __builtin_bit_cast(bf16x8, Bp[kc]), acc0, 0, 0, 0);
            acc1 = __builtin_amdgcn_mfma_f32_32x32x16_bf16(
                __builtin_bit_cast(bf16x8, Ap[1][kc]),
                __builtin_bit_cast(bf16x8, Bp[kc]), acc1, 0, 0, 0);
        }
        const bool doRescale = ((tau & 3) == 0);
        const bool doMeasure = ((tau & 3) == 2);
        float rr = 1.0f;
        if (doRescale) {
            rr = 1.0f / wm;
            sig_w += __logf(wm);
        }
        float lmax = 0.f;
#pragma unroll
        for (int I = 0; I < 2; ++I)
#pragma unroll
            for (int rg = 0; rg < 4; ++rg) {
                const int k0 = 32 * I + 8 * rg + 4 * h;
                float4 G = *(const float4*)&gtab[tau * 64 + k0];
                float v0 = (I ? acc1 : acc0)[4 * rg + 0] * (G.x * rr);
                float v1 = (I ? acc1 : acc0)[4 * rg + 1] * (G.y * rr);
                float v2 = (I ? acc1 : acc0)[4 * rg + 2] * (G.z * rr);
                float v3 = (I ? acc1 : acc0)[4 * rg + 3] * (G.w * rr);
                if (doMeasure) lmax = fmaxf(lmax, fmaxf(fmaxf(v0, v1), fmaxf(v2, v3)));
                P[I][rg] = make_uint2(packbf(v0, v1), packbf(v2, v3));
            }
        if (doMeasure) wm = waveMaxF(lmax);
    }

    // ---- spill P to Qlds once, then per-row normalize + store
#pragma unroll
    for (int I = 0; I < 2; ++I)
#pragma unroll
        for (int rg = 0; rg < 4; ++rg) {
            const int k0 = 32 * I + 8 * rg + 4 * h;
            *(uint2*)&Qlds[n * QP + k0] = P[I][rg];
        }
    if (L == 0) sigLDS[J] = sig_w;
    __syncthreads();
    const float sg0 = sigLDS[0], sg1 = sigLDS[1];
    const float smax = fmaxf(sg0, sg1);
    const float fh = __expf((hi ? sg1 : sg0) - smax);
    const int r = 32 * J + c31;
    float rv[32];
    float lmaxr = 0.f;
#pragma unroll
    for (int i = 0; i < 32; ++i) {
        float v = __uint_as_float(((u32)Qlds[(32 * h + i) * QP + r]) << 16) * fh;
        rv[i] = v;
        lmaxr = fmaxf(lmaxr, v);
    }
    float rmax = fmaxf(lmaxr, __shfl_xor(lmaxr, 32, 64));
    float inv = (rmax > 0.f) ? 1.0f / rmax : 0.f;
    float sj = (rmax > 0.f) ? smax + __logf(rmax) : 0.f;
    u32* og = (u32*)out + (size_t)b * (Tn * Ln) + (size_t)cix * (CK * Ln) + r * 32 + h * 16;
#pragma unroll
    for (int w8 = 0; w8 < 4; ++w8) {
        uint4 w;
        w.x = packbf(rv[8 * w8 + 0] * inv, rv[8 * w8 + 1] * inv);
        w.y = packbf(rv[8 * w8 + 2] * inv, rv[8 * w8 + 3] * inv);
        w.z = packbf(rv[8 * w8 + 4] * inv, rv[8 * w8 + 5] * inv);
        w.w = packbf(rv[8 * w8 + 6] * inv, rv[8 * w8 + 7] * inv);
        *(uint4*)(og + 4 * w8) = w;
    }
    if (h == 0) wsS[b * 1024 + cix * 64 + r] = sj;
}

// ================= PASS B: serial boundary combine (unchanged) =================
__global__ __launch_bounds__(64) void crf_passB(const float* __restrict__ out,
                                                float* __restrict__ wsE,
                                                const float* __restrict__ wsS) {
    const int b = blockIdx.x;
    const int j = threadIdx.x;
    __shared__ alignas(16) float uL[64];
    const u32* Qbase = (const u32*)out + (size_t)b * (Tn * Ln);

    float e = wsE[b * 1024 + 1 * 64 + j];
    uint4 nxt[8];
    float signxt = wsS[b * 1024 + 1 * 64 + j];
#pragma unroll
    for (int r = 0; r < 8; ++r) nxt[r] = *(const uint4*)(Qbase + 1 * (CK * Ln) + j * 32 + 4 * r);

#pragma unroll
    for (int c = 1; c <= 14; ++c) {
        uint4 cur[8];
#pragma unroll
        for (int r = 0; r < 8; ++r) cur[r] = nxt[r];
        float sig = signxt;
        if (c < 14) {
#pragma unroll
            for (int r = 0; r < 8; ++r)
                nxt[r] = *(const uint4*)(Qbase + (size_t)(c + 1) * (CK * Ln) + j * 32 + 4 * r);
            signxt = wsS[b * 1024 + (c + 1) * 64 + j];
        }
        float m = __shfl(e, 1, 64);
        uL[j] = __expf(e - m);
        const float4* u4 = reinterpret_cast<const float4*>(uL);
        float S = 0.f;
#pragma unroll
        for (int i4 = 0; i4 < 16; ++i4) {
            float4 uv = u4[i4];
            u32 d0 = ((const u32*)cur)[2 * i4];
            u32 d1 = ((const u32*)cur)[2 * i4 + 1];
            S = fmaf(uv.x, lo16f(d0), S);
            S = fmaf(uv.y, hi16f(d0), S);
            S = fmaf(uv.z, lo16f(d1), S);
            S = fmaf(uv.w, hi16f(d1), S);
        }
        float a;
        if (S > 0.f) a = m + sig + __logf(S);
        else a = m + NEGV + ((j == 0) ? NEGV : 0.f);
        e = a;
        wsE[b * 1024 + (c + 1) * 64 + j] = e;
    }
}

// ====== PASS C: batch-matrix MFMA alpha recompute, LDS-staged coalesced I/O ======
// 30 blocks: block = (chunk cix, batch-half J), 1 wave each. All LDS wave-private.
__global__ __launch_bounds__(64) void crf_passC(const float* __restrict__ em,
                                                const float* __restrict__ tr,
                                                float* __restrict__ out,
                                                const float* __restrict__ wsE) {
    const int cix = 1 + (blockIdx.x >> 1);   // 1..15
    const int J = blockIdx.x & 1;            // batch half
    const int L = threadIdx.x;
    const int h = L >> 5, c31 = L & 31;
    const bool hi = (h != 0);
    const int b = 32 * J + c31;              // this lane's batch (MFMA column)
    const int r = c31;                       // row in the staging tiles
    const int t0 = CK * cix;

    // staging tiles: [32 rows][17 chunks][4 floats]; pitch 17 -> bank 4(r+c) mod 32, uniform
    __shared__ alignas(16) float emS[2][32 * 17 * 4];
    __shared__ alignas(16) float alS[32 * 17 * 4];

    // A-frags: E^T (same as passA)
    uint4 Ap[2][4];
#pragma unroll
    for (int I = 0; I < 2; ++I)
#pragma unroll
        for (int kc = 0; kc < 4; ++kc) {
            float e[8];
#pragma unroll
            for (int q = 0; q < 8; ++q) {
                int k = 16 * kc + 8 * h + q;
                e[q] = __expf(tr[k * Ln + 32 * I + c31]);
            }
            Ap[I][kc] = make_uint4(packbf(e[0], e[1]), packbf(e[2], e[3]),
                                   packbf(e[4], e[5]), packbf(e[6], e[7]));
        }

    // entry: V0[k][b] = exp(alpha_entry[k] - sigma_b)
    const float* we = wsE + b * 1024 + cix * 64;
    float sig;
    uint2 P[2][4];
    {
        float4 av[2][4];
        float mx = -3e38f;
#pragma unroll
        for (int I = 0; I < 2; ++I)
#pragma unroll
            for (int rg = 0; rg < 4; ++rg) {
                const int k0 = 32 * I + 8 * rg + 4 * h;
                float4 a4 = *(const float4*)&we[k0];
                av[I][rg] = a4;
                mx = fmaxf(mx, fmaxf(fmaxf(a4.x, a4.y), fmaxf(a4.z, a4.w)));
            }
        mx = fmaxf(mx, __shfl_xor(mx, 32, 64));
        sig = mx;
#pragma unroll
        for (int I = 0; I < 2; ++I)
#pragma unroll
            for (int rg = 0; rg < 4; ++rg) {
                float4 a4 = av[I][rg];
                float v0 = fexp2((a4.x - sig) * L2E), v1 = fexp2((a4.y - sig) * L2E);
                float v2 = fexp2((a4.z - sig) * L2E), v3 = fexp2((a4.w - sig) * L2E);
                P[I][rg] = make_uint2(packbf(v0, v1), packbf(v2, v3));
            }
    }

    // preamble: stage em slice t0 into slot 0 (coalesced: 16 lanes per batch-row)
#pragma unroll
    for (int i = 0; i < 8; ++i) {
        int q = 64 * i + L;
        int rw = q >> 4, cc = q & 15;
        float4 v = *(const float4*)&em[(((size_t)(32 * J + rw)) * Tn + t0) * Ln + 4 * cc];
        *(float4*)&emS[0][(rw * 17 + cc) * 4] = v;
    }

    float wmUse = 1.0f;
    const f32x16 Z = (f32x16)(0.0f);
    for (int tau = 0; tau < CK; ++tau) {
        const int slot = tau & 1;
        // issue next-slice loads now; ds_write them at the bottom (hide vmcnt behind the step)
        float4 ld[8];
        if (tau + 1 < CK) {
#pragma unroll
            for (int i = 0; i < 8; ++i) {
                int q = 64 * i + L;
                int rw = q >> 4, cc = q & 15;
                ld[i] = *(const float4*)&em[(((size_t)(32 * J + rw)) * Tn + (t0 + tau + 1)) * Ln + 4 * cc];
            }
        }
        const bool even = ((tau & 1) == 0);
        float rrs = 1.0f, dsig = 0.0f;
        if (even && tau >= 2) {
            rrs = 1.0f / wmUse;
            dsig = LN2 * flog2(wmUse);
        }
        uint4 Bp[4];
#pragma unroll
        for (int kc = 0; kc < 4; ++kc) {
            const int I = kc >> 1;
            const int rgB = 2 * (kc & 1);
            uint2 pe2 = P[I][rgB];
            uint2 po2 = P[I][rgB + 1];
            uint2 keep, send;
            keep.x = hi ? po2.x : pe2.x;  keep.y = hi ? po2.y : pe2.y;
            send.x = hi ? pe2.x : po2.x;  send.y = hi ? pe2.y : po2.y;
            uint2 recv;
            recv.x = (u32)__shfl_xor((int)send.x, 32, 64);
            recv.y = (u32)__shfl_xor((int)send.y, 32, 64);
            Bp[kc].x = hi ? recv.x : keep.x;
            Bp[kc].y = hi ? recv.y : keep.y;
            Bp[kc].z = hi ? keep.x : recv.x;
            Bp[kc].w = hi ? keep.y : recv.y;
        }
        f32x16 acc0 = Z, acc1 = Z;
#pragma unroll
        for (int kc = 0; kc < 4; ++kc) {
            acc0 = __builtin_amdgcn_mfma_f32_32x32x16_bf16(
                __builtin_bit_cast(bf16x8, Ap[0][kc]),
                __builtin_bit_cast(bf16x8, Bp[kc]), acc0, 0, 0, 0);
            acc1 = __builtin_amdgcn_mfma_f32_32x32x16_bf16(
                __builtin_bit_cast(bf16x8, Ap[1][kc]),
                __builtin_bit_cast(bf16x8, Bp[kc]), acc1, 0, 0, 0);
        }
        float lmax = 0.f;
#pragma unroll
        for (int I = 0; I < 2; ++I)
#pragma unroll
            for (int rg = 0; rg < 4; ++rg) {
                const int k0 = 32 * I + 8 * rg + 4 * h;
                const int c = 8 * I + 2 * rg + h;       // k0 >> 2
                float4 ev = *(const float4*)&emS[slot][(r * 17 + c) * 4];
                if (k0 == 0) ev.x = NEGV;               // n==0  (START col)
                if (k0 == 60) ev.w = NEGV;              // n==63 (END col)
                float c0 = (I ? acc1 : acc0)[4 * rg + 0];
                float c1 = (I ? acc1 : acc0)[4 * rg + 1];
                float c2 = (I ? acc1 : acc0)[4 * rg + 2];
                float c3 = (I ? acc1 : acc0)[4 * rg + 3];
                float4 al;
                al.x = ev.x + ((c0 > 0.f) ? LN2 * flog2(c0) + sig : NEGV);
                al.y = ev.y + ((c1 > 0.f) ? LN2 * flog2(c1) + sig : NEGV);
                al.z = ev.z + ((c2 > 0.f) ? LN2 * flog2(c2) + sig : NEGV);
                al.w = ev.w + ((c3 > 0.f) ? LN2 * flog2(c3) + sig : NEGV);
                *(float4*)&alS[(r * 17 + c) * 4] = al;
                float v0 = c0 * (fexp2(ev.x * L2E) * rrs);
                float v1 = c1 * (fexp2(ev.y * L2E) * rrs);
                float v2 = c2 * (fexp2(ev.z * L2E) * rrs);
                float v3 = c3 * (fexp2(ev.w * L2E) * rrs);
                if (even) lmax = fmaxf(lmax, fmaxf(fmaxf(v0, v1), fmaxf(v2, v3)));
                P[I][rg] = make_uint2(packbf(v0, v1), packbf(v2, v3));
            }
        if (even) wmUse = fmaxf(lmax, __shfl_xor(lmax, 32, 64));
        sig += dsig;                                    // applies to V_new (next step's input)

        // drain alS -> out, coalesced (wave-internal in-order DS: no barrier needed)
#pragma unroll
        for (int i = 0; i < 8; ++i) {
            int q = 64 * i + L;
            int rw = q >> 4, cc = q & 15;
            float4 v = *(const float4*)&alS[(rw * 17 + cc) * 4];
            *(float4*)&out[(((size_t)(32 * J + rw)) * Tn + (t0 + tau)) * Ln + 4 * cc] = v;
        }
        // commit next em slice into the other slot
        if (tau + 1 < CK) {
#pragma unroll
            for (int i = 0; i < 8; ++i) {
                int q = 64 * i + L;
                int rw = q >> 4, cc = q & 15;
                *(float4*)&emS[slot ^ 1][(rw * 17 + cc) * 4] = ld[i];
            }
        }
    }
}

// ================= PASS D: logZ from finished alphas =================
__global__ __launch_bounds__(64) void crf_logZ(const float* __restrict__ tr,
                                               const int* __restrict__ lens,
                                               float* __restrict__ out) {
    const int b = blockIdx.x;
    const int j = threadIdx.x;
    float a = out[(size_t)b * Tn * Ln + (size_t)(lens[b] - 1) * Ln + j] + tr[j * Ln + (Ln - 1)];
    float m2 = waveMaxF(a);
    float e2 = __expf(a - m2);
#pragma unroll
    for (int off = 32; off > 0; off >>= 1)
        e2 += __shfl_xor(e2, off, 64);
    if (j == 0) out[(size_t)Bn * Tn * Ln + b] = m2 + __logf(e2);
}

// ================= fallback: round-2 single kernel =================
__global__ __launch_bounds__(64) void crf_fallback(const float* __restrict__ em,
                                                   const float* __restrict__ tr,
                                                   const int* __restrict__ lens,
                                                   float* __restrict__ out) {
    const int b = blockIdx.x;
    const int j = threadIdx.x;
    __shared__ alignas(16) float uLDS[Ln];
    float E[Ln];
#pragma unroll
    for (int i = 0; i < Ln; ++i) E[i] = __expf(tr[i * Ln + j]);
    const float trSj = tr[j];
    const float trEj = tr[j * Ln + (Ln - 1)];
    const int len = lens[b];
    const bool edge = (j == 0) || (j == Ln - 1);
    const float* emb = em + (size_t)b * Tn * Ln;
    float* outb = out + (size_t)b * Tn * Ln;
    float emq[4];
#pragma unroll
    for (int tt = 0; tt < 4; ++tt) {
        float v = emb[tt * Ln + j];
        emq[tt] = edge ? NEGV : v;
    }
    float a = trSj + emq[0];
    outb[j] = a;
    float aPrev = a, aLast = a;
    float mPrev = __shfl(a, 1, 64);
    float u = __expf(a - mPrev);
#pragma unroll 4
    for (int t = 1; t < Tn; ++t) {
        uLDS[j] = u;
        const float em_t = emq[t & 3];
        const int tp = t + 4;
        if (tp < Tn) {
            float v = emb[tp * Ln + j];
            emq[tp & 3] = edge ? NEGV : v;
        }
        float mNext = __shfl(aPrev, 1, 64);
        float cf = __expf(em_t + (mPrev - mNext));
        float acc0 = 0.f, acc1 = 0.f, acc2 = 0.f, acc3 = 0.f;
        const float4* u4 = reinterpret_cast<const float4*>(uLDS);
#pragma unroll
        for (int i4 = 0; i4 < 16; ++i4) {
            float4 uv = u4[i4];
            acc0 = fmaf(uv.x, E[4 * i4 + 0], acc0);
            acc1 = fmaf(uv.y, E[4 * i4 + 1], acc1);
            acc2 = fmaf(uv.z, E[4 * i4 + 2], acc2);
            acc3 = fmaf(uv.w, E[4 * i4 + 3], acc3);
        }
        float S = (acc0 + acc1) + (acc2 + acc3);
        float lg = __logf(S);
        lg = (S > 0.f) ? lg : NEGV;
        float a_t = em_t + (mPrev + lg);
        outb[t * Ln + j] = a_t;
        if (t == len - 1) aLast = a_t;
        u = S * cf;
        aPrev = a_t;
        mPrev = mNext;
    }
    float last = aLast + trEj;
    float m2 = last;
#pragma unroll
    for (int off = 32; off > 0; off >>= 1)
        m2 = fmaxf(m2, __shfl_xor(m2, off, 64));
    float e2 = __expf(last - m2);
#pragma unroll
    for (int off = 32; off > 0; off >>= 1)
        e2 += __shfl_xor(e2, off, 64);
    if (j == 0) out[(size_t)Bn * Tn * Ln + b] = m2 + __logf(e2);
}

extern "C" void kernel_launch(void* const* d_in, const int* in_sizes, int n_in,
                              void* d_out, int out_size, void* d_ws, size_t ws_size,
                              hipStream_t stream) {
    const float* em = (const float*)d_in[0];
    const float* tr = (const float*)d_in[1];
    const int* lens = (const int*)d_in[2];
    float* out = (float*)d_out;
    const size_t wsNeed = 2u * 64 * 16 * 64 * sizeof(float);   // 512 KiB
    if (ws_size >= wsNeed) {
        float* wsE = (float*)d_ws;
        float* wsS = wsE + 64 * 16 * 64;
        crf_passA<<<dim3(1024), dim3(128), 0, stream>>>(em, tr, out, wsE, wsS);
        crf_passB<<<dim3(64), dim3(64), 0, stream>>>(out, wsE, wsS);
        crf_passC<<<dim3(30), dim3(64), 0, stream>>>(em, tr, out, wsE);
        crf_logZ<<<dim3(64), dim3(64), 0, stream>>>(tr, lens, out);
    } else {
        crf_fallback<<<dim3(Bn), dim3(64), 0, stream>>>(em, tr, lens, out);
    }
}